// Round 1
// baseline (1553.750 us; speedup 1.0000x reference)
//
#include <hip/hip_runtime.h>
#include <cstdint>
#include <cstddef>

#define FDIM 128

// ---------------- CSR build ----------------

__global__ __launch_bounds__(256) void k_count(const int* __restrict__ dst, int e,
                                               int* __restrict__ deg) {
  int i = blockIdx.x * 256 + threadIdx.x;
  if (i < e) atomicAdd(&deg[dst[i]], 1);
}

// Per-block exclusive scan of degrees; block base allocated by atomic bump.
// Segment order across blocks is scrambled but segments are disjoint: fine.
__global__ __launch_bounds__(256) void k_alloc(const int* __restrict__ deg,
                                               int* __restrict__ rowStart,
                                               int* __restrict__ writeOff,
                                               int* __restrict__ counter,
                                               float* __restrict__ dis, int n) {
  __shared__ int s[256];
  __shared__ int base_s;
  int i = blockIdx.x * 256 + threadIdx.x;
  int v = (i < n) ? deg[i] : 0;
  int x = v;
  s[threadIdx.x] = x;
  __syncthreads();
  for (int off = 1; off < 256; off <<= 1) {
    int t = (threadIdx.x >= off) ? s[threadIdx.x - off] : 0;
    __syncthreads();
    x += t;
    s[threadIdx.x] = x;
    __syncthreads();
  }
  if (threadIdx.x == 255) base_s = atomicAdd(counter, x);  // x == block total
  __syncthreads();
  if (i < n) {
    int start = base_s + x - v;  // exclusive scan + block base
    rowStart[i] = start;
    writeOff[i] = start;
    dis[i] = 1.0f / sqrtf((float)(v + 1));  // deg_hat includes self-loop
  }
}

__global__ __launch_bounds__(256) void k_fill(const int* __restrict__ src,
                                              const int* __restrict__ dst, int e,
                                              int* __restrict__ writeOff,
                                              int* __restrict__ colIdx) {
  int i = blockIdx.x * 256 + threadIdx.x;
  if (i < e) {
    int pos = atomicAdd(&writeOff[dst[i]], 1);
    colIdx[pos] = src[i];
  }
}

// ---------------- dense matmul: O[n,128] = A[n,128] @ W[128,128] ----------------
// fp32 VALU (no fp32 MFMA on CDNA4). W-half (128x64) staged in LDS (32KB),
// 32 A-rows staged (padded stride 132 to dodge bank conflicts). Each thread:
// 2 rows x 4 cols register tile. Col-halves looped to stay well under 64KB LDS.
__global__ __launch_bounds__(256) void k_matmul(const float* __restrict__ A,
                                                const float* __restrict__ W,
                                                float* __restrict__ O, int n) {
  __shared__ float Ws[FDIM * 64];   // [k][c] for one col-half, 32 KB
  __shared__ float As[32 * 132];    // 32 rows, stride 132 (16B aligned, conflict-free)
  int c4 = (threadIdx.x & 15) * 4;  // col quad within half
  int rp = threadIdx.x >> 4;        // row pair 0..15

  for (int ch = 0; ch < 2; ++ch) {
    __syncthreads();
    for (int q = threadIdx.x; q < FDIM * 16; q += 256) {  // 128x64 / 4
      int k = q >> 4, c = (q & 15) * 4;
      *(float4*)&Ws[k * 64 + c] = *(const float4*)&W[k * FDIM + ch * 64 + c];
    }
    __syncthreads();

    for (int r0 = blockIdx.x * 32; r0 < n; r0 += gridDim.x * 32) {
      __syncthreads();
      int nr = min(32, n - r0);
      for (int q = threadIdx.x; q < nr * 32; q += 256) {
        int r = q >> 5, c = (q & 31) * 4;
        *(float4*)&As[r * 132 + c] = *(const float4*)&A[(size_t)(r0 + r) * FDIM + c];
      }
      __syncthreads();

      int row = r0 + 2 * rp;
      if (row < n) {
        float4 acc0 = {0.f, 0.f, 0.f, 0.f};
        float4 acc1 = {0.f, 0.f, 0.f, 0.f};
#pragma unroll
        for (int k = 0; k < FDIM; k += 4) {
          float4 w0 = *(const float4*)&Ws[(k + 0) * 64 + c4];
          float4 w1 = *(const float4*)&Ws[(k + 1) * 64 + c4];
          float4 w2 = *(const float4*)&Ws[(k + 2) * 64 + c4];
          float4 w3 = *(const float4*)&Ws[(k + 3) * 64 + c4];
          float4 a0 = *(const float4*)&As[(2 * rp) * 132 + k];
          float4 a1 = *(const float4*)&As[(2 * rp + 1) * 132 + k];
          acc0.x += a0.x * w0.x + a0.y * w1.x + a0.z * w2.x + a0.w * w3.x;
          acc0.y += a0.x * w0.y + a0.y * w1.y + a0.z * w2.y + a0.w * w3.y;
          acc0.z += a0.x * w0.z + a0.y * w1.z + a0.z * w2.z + a0.w * w3.z;
          acc0.w += a0.x * w0.w + a0.y * w1.w + a0.z * w2.w + a0.w * w3.w;
          acc1.x += a1.x * w0.x + a1.y * w1.x + a1.z * w2.x + a1.w * w3.x;
          acc1.y += a1.x * w0.y + a1.y * w1.y + a1.z * w2.y + a1.w * w3.y;
          acc1.z += a1.x * w0.z + a1.y * w1.z + a1.z * w2.z + a1.w * w3.z;
          acc1.w += a1.x * w0.w + a1.y * w1.w + a1.z * w2.w + a1.w * w3.w;
        }
        *(float4*)&O[(size_t)row * FDIM + ch * 64 + c4] = acc0;
        if (row + 1 < n)
          *(float4*)&O[(size_t)(row + 1) * FDIM + ch * 64 + c4] = acc1;
      }
    }
  }
}

// ---------------- aggregation (pull) + bias + ReLU ----------------
// One wave per node, lane handles 2 features (float2). agg[i] =
// dis[i]^2*h[i] + sum_j dis[i]*dis[src_j]*h[src_j]; then +b, relu.
__global__ __launch_bounds__(256) void k_agg(const float* __restrict__ Hin,
                                             float* __restrict__ Hout,
                                             const int* __restrict__ rowStart,
                                             const int* __restrict__ degE,
                                             const int* __restrict__ colIdx,
                                             const float* __restrict__ dis,
                                             const float* __restrict__ bias, int n) {
  int node = blockIdx.x * 4 + (threadIdx.x >> 6);
  int lane = threadIdx.x & 63;
  if (node >= n) return;
  const float2* hin2 = (const float2*)Hin;
  float di = dis[node];
  float2 self = hin2[(size_t)node * 64 + lane];
  float ws = di * di;
  float ax = ws * self.x, ay = ws * self.y;
  int s0 = rowStart[node], cnt = degE[node];
#pragma unroll 4
  for (int j = 0; j < cnt; ++j) {
    int s = colIdx[s0 + j];
    float w = di * dis[s];
    float2 hv = hin2[(size_t)s * 64 + lane];
    ax += w * hv.x;
    ay += w * hv.y;
  }
  float2 b = ((const float2*)bias)[lane];
  ax = fmaxf(ax + b.x, 0.f);
  ay = fmaxf(ay + b.y, 0.f);
  float2 o;
  o.x = ax;
  o.y = ay;
  ((float2*)Hout)[(size_t)node * 64 + lane] = o;
}

// ---------------- pooling ----------------

__global__ __launch_bounds__(128) void k_gstart(const int* __restrict__ batch, int n,
                                                int g_count, int* __restrict__ gstart) {
  int g = threadIdx.x;
  if (g > g_count) return;
  int lo = 0, hi = n;
  while (lo < hi) {
    int mid = (lo + hi) >> 1;
    if (batch[mid] < g) lo = mid + 1;
    else hi = mid;
  }
  gstart[g] = lo;
}

__global__ __launch_bounds__(128) void k_pool(const float* __restrict__ H,
                                              const int* __restrict__ gstart,
                                              float* __restrict__ pooled, int g_count) {
  int g = blockIdx.x >> 4;
  int c = blockIdx.x & 15;
  int s = gstart[g], e = gstart[g + 1];
  int len = e - s;
  int chunk = (len + 15) >> 4;
  int ns = s + c * chunk;
  int ne = min(ns + chunk, e);
  float acc = 0.f;
  for (int i = ns; i < ne; ++i) acc += H[(size_t)i * FDIM + threadIdx.x];
  atomicAdd(&pooled[g * FDIM + threadIdx.x], acc);
}

__global__ __launch_bounds__(192) void k_final(const float* __restrict__ pooled,
                                               const int* __restrict__ gstart,
                                               const float* __restrict__ Wc,
                                               const float* __restrict__ bc,
                                               float* __restrict__ out, int g_count) {
  int t = threadIdx.x;
  if (t >= g_count * 3) return;
  int g = t / 3, c = t % 3;
  int cnt = gstart[g + 1] - gstart[g];
  float inv = 1.0f / (float)max(cnt, 1);
  float acc = bc[c];
#pragma unroll 8
  for (int k = 0; k < FDIM; ++k) acc += pooled[g * FDIM + k] * inv * Wc[k * 3 + c];
  out[g * 3 + c] = acc;
}

// ---------------- host ----------------

extern "C" void kernel_launch(void* const* d_in, const int* in_sizes, int n_in,
                              void* d_out, int out_size, void* d_ws, size_t ws_size,
                              hipStream_t stream) {
  const float* x = (const float*)d_in[0];
  const int* edge = (const int*)d_in[1];
  const int* batch = (const int*)d_in[2];
  const float* W1 = (const float*)d_in[3];
  const float* b1 = (const float*)d_in[4];
  const float* W2 = (const float*)d_in[5];
  const float* b2 = (const float*)d_in[6];
  const float* W3 = (const float*)d_in[7];
  const float* b3 = (const float*)d_in[8];
  const float* Wc = (const float*)d_in[9];
  const float* bc = (const float*)d_in[10];
  float* out = (float*)d_out;

  const int N = in_sizes[0] / FDIM;
  const int E = in_sizes[1] / 2;
  const int G = out_size / 3;
  const int* src = edge;
  const int* dst = edge + E;

  char* ws = (char*)d_ws;
  size_t off = 0;
  auto carve = [&](size_t bytes) -> void* {
    void* p = ws + off;
    off = (off + bytes + 255) & ~(size_t)255;
    return p;
  };
  float* h0 = (float*)carve((size_t)N * FDIM * 4);
  float* h1 = (float*)carve((size_t)N * FDIM * 4);
  int* colIdx = (int*)carve((size_t)E * 4);
  int* deg = (int*)carve((size_t)N * 4);
  int* rowStart = (int*)carve((size_t)N * 4);
  int* writeOff = (int*)carve((size_t)N * 4);
  float* dis = (float*)carve((size_t)N * 4);
  int* counter = (int*)carve(256);
  int* gstart = (int*)carve((size_t)(G + 1) * 4);
  float* pooled = (float*)carve((size_t)G * FDIM * 4);
  (void)n_in;
  (void)ws_size;

  hipMemsetAsync(deg, 0, (size_t)N * 4, stream);
  hipMemsetAsync(counter, 0, 4, stream);
  hipMemsetAsync(pooled, 0, (size_t)G * FDIM * 4, stream);

  int eb = (E + 255) / 256;
  int nb = (N + 255) / 256;
  k_count<<<eb, 256, 0, stream>>>(dst, E, deg);
  k_alloc<<<nb, 256, 0, stream>>>(deg, rowStart, writeOff, counter, dis, N);
  k_fill<<<eb, 256, 0, stream>>>(src, dst, E, writeOff, colIdx);

  k_matmul<<<1563, 256, 0, stream>>>(x, W1, h0, N);
  k_agg<<<(N + 3) / 4, 256, 0, stream>>>(h0, h1, rowStart, deg, colIdx, dis, b1, N);
  k_matmul<<<1563, 256, 0, stream>>>(h1, W2, h0, N);
  k_agg<<<(N + 3) / 4, 256, 0, stream>>>(h0, h1, rowStart, deg, colIdx, dis, b2, N);
  k_matmul<<<1563, 256, 0, stream>>>(h1, W3, h0, N);
  k_agg<<<(N + 3) / 4, 256, 0, stream>>>(h0, h1, rowStart, deg, colIdx, dis, b3, N);

  k_gstart<<<1, 128, 0, stream>>>(batch, N, G, gstart);
  k_pool<<<G * 16, 128, 0, stream>>>(h1, gstart, pooled, G);
  k_final<<<1, 192, 0, stream>>>(pooled, gstart, Wc, bc, out, G);
}

// Round 2
// 921.381 us; speedup vs baseline: 1.6863x; 1.6863x over previous
//
#include <hip/hip_runtime.h>
#include <cstdint>
#include <cstddef>

#define FDIM 128

// ---------------- CSR build ----------------

__global__ __launch_bounds__(256) void k_count(const int* __restrict__ dst, int e,
                                               int* __restrict__ deg) {
  int i = blockIdx.x * 256 + threadIdx.x;
  if (i < e) atomicAdd(&deg[dst[i]], 1);
}

// Per-block exclusive scan of degrees; block base allocated by atomic bump.
// Segment order across blocks is scrambled but segments are disjoint: fine.
__global__ __launch_bounds__(256) void k_alloc(const int* __restrict__ deg,
                                               int* __restrict__ rowStart,
                                               int* __restrict__ writeOff,
                                               int* __restrict__ counter,
                                               float* __restrict__ dis, int n) {
  __shared__ int s[256];
  __shared__ int base_s;
  int i = blockIdx.x * 256 + threadIdx.x;
  int v = (i < n) ? deg[i] : 0;
  int x = v;
  s[threadIdx.x] = x;
  __syncthreads();
  for (int off = 1; off < 256; off <<= 1) {
    int t = (threadIdx.x >= off) ? s[threadIdx.x - off] : 0;
    __syncthreads();
    x += t;
    s[threadIdx.x] = x;
    __syncthreads();
  }
  if (threadIdx.x == 255) base_s = atomicAdd(counter, x);  // x == block total
  __syncthreads();
  if (i < n) {
    int start = base_s + x - v;  // exclusive scan + block base
    rowStart[i] = start;
    writeOff[i] = start;
    dis[i] = 1.0f / sqrtf((float)(v + 1));  // deg_hat includes self-loop
  }
}

__global__ __launch_bounds__(256) void k_fill(const int* __restrict__ src,
                                              const int* __restrict__ dst, int e,
                                              int* __restrict__ writeOff,
                                              int* __restrict__ colIdx) {
  int i = blockIdx.x * 256 + threadIdx.x;
  if (i < e) {
    int pos = atomicAdd(&writeOff[dst[i]], 1);
    colIdx[pos] = src[i];
  }
}

// ---------------- dense matmul: O[n,128] = A[n,128] @ W[128,128] ----------------
// fp32 VALU (no fp32 MFMA on CDNA4). Full W (64 KB) in LDS. 64-row tile per
// block; thread tile 4 rows x 8 cols. A read straight from global (16 lanes
// share each address -> merges to one request; tile is L1/L2 resident) with
// one-chunk software prefetch. k-loop NOT unrolled (previous version's full
// unroll spilled: VGPR=256, WRITE_SIZE 438MB vs 51MB ideal).
__global__ __launch_bounds__(256) void k_matmul(const float* __restrict__ A,
                                                const float* __restrict__ W,
                                                float* __restrict__ O, int n) {
  __shared__ float Ws[FDIM * FDIM];  // 64 KB -> 2 blocks/CU
  int tid = threadIdx.x;
  for (int q = tid; q < FDIM * (FDIM / 4); q += 256) {
    int k = q >> 5, c = (q & 31) << 2;
    *(float4*)&Ws[k * FDIM + c] = *(const float4*)&W[k * FDIM + c];
  }
  __syncthreads();
  int tr = tid >> 4;         // 0..15
  int tc = (tid & 15) << 3;  // col base 0,8,...,120

  for (int r0 = blockIdx.x * 64; r0 < n; r0 += gridDim.x * 64) {
    int rbase = r0 + tr * 4;
    float acc[4][8];
#pragma unroll
    for (int r = 0; r < 4; ++r)
#pragma unroll
      for (int c = 0; c < 8; ++c) acc[r][c] = 0.f;

    float4 a_cur[4], a_nxt[4];
#pragma unroll
    for (int r = 0; r < 4; ++r)
      a_cur[r] = (rbase + r < n) ? *(const float4*)&A[(size_t)(rbase + r) * FDIM]
                                 : float4{0.f, 0.f, 0.f, 0.f};

#pragma unroll 1
    for (int k = 0; k < FDIM; k += 4) {
      if (k + 4 < FDIM) {
#pragma unroll
        for (int r = 0; r < 4; ++r)
          a_nxt[r] = (rbase + r < n)
                         ? *(const float4*)&A[(size_t)(rbase + r) * FDIM + k + 4]
                         : float4{0.f, 0.f, 0.f, 0.f};
      }
#pragma unroll
      for (int kk = 0; kk < 4; ++kk) {
        float4 w0 = *(const float4*)&Ws[(k + kk) * FDIM + tc];
        float4 w1 = *(const float4*)&Ws[(k + kk) * FDIM + tc + 4];
#pragma unroll
        for (int r = 0; r < 4; ++r) {
          float av = (&a_cur[r].x)[kk];
          acc[r][0] += av * w0.x;
          acc[r][1] += av * w0.y;
          acc[r][2] += av * w0.z;
          acc[r][3] += av * w0.w;
          acc[r][4] += av * w1.x;
          acc[r][5] += av * w1.y;
          acc[r][6] += av * w1.z;
          acc[r][7] += av * w1.w;
        }
      }
#pragma unroll
      for (int r = 0; r < 4; ++r) a_cur[r] = a_nxt[r];
    }

#pragma unroll
    for (int r = 0; r < 4; ++r) {
      if (rbase + r < n) {
        *(float4*)&O[(size_t)(rbase + r) * FDIM + tc] = *(float4*)&acc[r][0];
        *(float4*)&O[(size_t)(rbase + r) * FDIM + tc + 4] = *(float4*)&acc[r][4];
      }
    }
  }
}

// ---------------- aggregation (pull) + bias + ReLU ----------------
// One wave per node, lane handles 2 features (float2). agg[i] =
// dis[i]^2*h[i] + sum_j dis[i]*dis[src_j]*h[src_j]; then +b, relu.
__global__ __launch_bounds__(256) void k_agg(const float* __restrict__ Hin,
                                             float* __restrict__ Hout,
                                             const int* __restrict__ rowStart,
                                             const int* __restrict__ degE,
                                             const int* __restrict__ colIdx,
                                             const float* __restrict__ dis,
                                             const float* __restrict__ bias, int n) {
  int node = blockIdx.x * 4 + (threadIdx.x >> 6);
  int lane = threadIdx.x & 63;
  if (node >= n) return;
  const float2* hin2 = (const float2*)Hin;
  float di = dis[node];
  float2 self = hin2[(size_t)node * 64 + lane];
  float ws = di * di;
  float ax = ws * self.x, ay = ws * self.y;
  int s0 = rowStart[node], cnt = degE[node];
#pragma unroll 4
  for (int j = 0; j < cnt; ++j) {
    int s = colIdx[s0 + j];
    float w = di * dis[s];
    float2 hv = hin2[(size_t)s * 64 + lane];
    ax += w * hv.x;
    ay += w * hv.y;
  }
  float2 b = ((const float2*)bias)[lane];
  ax = fmaxf(ax + b.x, 0.f);
  ay = fmaxf(ay + b.y, 0.f);
  float2 o;
  o.x = ax;
  o.y = ay;
  ((float2*)Hout)[(size_t)node * 64 + lane] = o;
}

// ---------------- pooling ----------------

__global__ __launch_bounds__(128) void k_gstart(const int* __restrict__ batch, int n,
                                                int g_count, int* __restrict__ gstart) {
  int g = threadIdx.x;
  if (g > g_count) return;
  int lo = 0, hi = n;
  while (lo < hi) {
    int mid = (lo + hi) >> 1;
    if (batch[mid] < g) lo = mid + 1;
    else hi = mid;
  }
  gstart[g] = lo;
}

__global__ __launch_bounds__(128) void k_pool(const float* __restrict__ H,
                                              const int* __restrict__ gstart,
                                              float* __restrict__ pooled, int g_count) {
  int g = blockIdx.x >> 4;
  int c = blockIdx.x & 15;
  int s = gstart[g], e = gstart[g + 1];
  int len = e - s;
  int chunk = (len + 15) >> 4;
  int ns = s + c * chunk;
  int ne = min(ns + chunk, e);
  float acc = 0.f;
  for (int i = ns; i < ne; ++i) acc += H[(size_t)i * FDIM + threadIdx.x];
  atomicAdd(&pooled[g * FDIM + threadIdx.x], acc);
}

__global__ __launch_bounds__(192) void k_final(const float* __restrict__ pooled,
                                               const int* __restrict__ gstart,
                                               const float* __restrict__ Wc,
                                               const float* __restrict__ bc,
                                               float* __restrict__ out, int g_count) {
  int t = threadIdx.x;
  if (t >= g_count * 3) return;
  int g = t / 3, c = t % 3;
  int cnt = gstart[g + 1] - gstart[g];
  float inv = 1.0f / (float)max(cnt, 1);
  float acc = bc[c];
#pragma unroll 8
  for (int k = 0; k < FDIM; ++k) acc += pooled[g * FDIM + k] * inv * Wc[k * 3 + c];
  out[g * 3 + c] = acc;
}

// ---------------- host ----------------

extern "C" void kernel_launch(void* const* d_in, const int* in_sizes, int n_in,
                              void* d_out, int out_size, void* d_ws, size_t ws_size,
                              hipStream_t stream) {
  const float* x = (const float*)d_in[0];
  const int* edge = (const int*)d_in[1];
  const int* batch = (const int*)d_in[2];
  const float* W1 = (const float*)d_in[3];
  const float* b1 = (const float*)d_in[4];
  const float* W2 = (const float*)d_in[5];
  const float* b2 = (const float*)d_in[6];
  const float* W3 = (const float*)d_in[7];
  const float* b3 = (const float*)d_in[8];
  const float* Wc = (const float*)d_in[9];
  const float* bc = (const float*)d_in[10];
  float* out = (float*)d_out;

  const int N = in_sizes[0] / FDIM;
  const int E = in_sizes[1] / 2;
  const int G = out_size / 3;
  const int* src = edge;
  const int* dst = edge + E;

  char* ws = (char*)d_ws;
  size_t off = 0;
  auto carve = [&](size_t bytes) -> void* {
    void* p = ws + off;
    off = (off + bytes + 255) & ~(size_t)255;
    return p;
  };
  float* h0 = (float*)carve((size_t)N * FDIM * 4);
  float* h1 = (float*)carve((size_t)N * FDIM * 4);
  int* colIdx = (int*)carve((size_t)E * 4);
  int* deg = (int*)carve((size_t)N * 4);
  int* rowStart = (int*)carve((size_t)N * 4);
  int* writeOff = (int*)carve((size_t)N * 4);
  float* dis = (float*)carve((size_t)N * 4);
  int* counter = (int*)carve(256);
  int* gstart = (int*)carve((size_t)(G + 1) * 4);
  float* pooled = (float*)carve((size_t)G * FDIM * 4);
  (void)n_in;
  (void)ws_size;

  hipMemsetAsync(deg, 0, (size_t)N * 4, stream);
  hipMemsetAsync(counter, 0, 4, stream);
  hipMemsetAsync(pooled, 0, (size_t)G * FDIM * 4, stream);

  int eb = (E + 255) / 256;
  int nb = (N + 255) / 256;
  k_count<<<eb, 256, 0, stream>>>(dst, E, deg);
  k_alloc<<<nb, 256, 0, stream>>>(deg, rowStart, writeOff, counter, dis, N);
  k_fill<<<eb, 256, 0, stream>>>(src, dst, E, writeOff, colIdx);

  int mmb = (N + 63) / 64;
  k_matmul<<<mmb, 256, 0, stream>>>(x, W1, h0, N);
  k_agg<<<(N + 3) / 4, 256, 0, stream>>>(h0, h1, rowStart, deg, colIdx, dis, b1, N);
  k_matmul<<<mmb, 256, 0, stream>>>(h1, W2, h0, N);
  k_agg<<<(N + 3) / 4, 256, 0, stream>>>(h0, h1, rowStart, deg, colIdx, dis, b2, N);
  k_matmul<<<mmb, 256, 0, stream>>>(h1, W3, h0, N);
  k_agg<<<(N + 3) / 4, 256, 0, stream>>>(h0, h1, rowStart, deg, colIdx, dis, b3, N);

  k_gstart<<<1, 128, 0, stream>>>(batch, N, G, gstart);
  k_pool<<<G * 16, 128, 0, stream>>>(h1, gstart, pooled, G);
  k_final<<<1, 192, 0, stream>>>(pooled, gstart, Wc, bc, out, G);
}

// Round 3
// 878.545 us; speedup vs baseline: 1.7685x; 1.0488x over previous
//
#include <hip/hip_runtime.h>
#include <cstdint>
#include <cstddef>

#define FDIM 128
#define CHUNK 4096   // edges per binning chunk
#define BSHIFT 8     // 256 nodes per bucket
#define BMASK 255
#define MAXB 512     // max buckets supported (N <= 131072)

// ---------------- CSR build (bucketed, scatter-free-ish) ----------------
// Round-2 k_fill did 1.6M random 4B writes -> 105MB HBM writeback (64B/line
// dirtied, partial lines never merge across XCD L2s). This pipeline makes
// every colIdx window the property of ONE block on ONE CU.

// Per-chunk histogram of dst buckets.
__global__ __launch_bounds__(256) void k_hist(const int* __restrict__ dst, int e,
                                              int nb, int* __restrict__ chunkHist) {
  __shared__ int h[MAXB];
  int c = blockIdx.x;
  int base = c * CHUNK;
  int end = min(base + CHUNK, e);
  for (int i = threadIdx.x; i < nb; i += 256) h[i] = 0;
  __syncthreads();
  for (int i = base + threadIdx.x; i < end; i += 256)
    atomicAdd(&h[dst[i] >> BSHIFT], 1);
  __syncthreads();
  for (int b = threadIdx.x; b < nb; b += 256)
    chunkHist[(size_t)c * nb + b] = h[b];
}

// Single block: chunkOff[c][b] = prefix over chunks; bucketBase[b] = prefix
// over buckets (== rowStart of bucket's first node, since CSR is bucket-major).
__global__ __launch_bounds__(512) void k_scan(const int* __restrict__ chunkHist,
                                              int nchunks, int nb, int e,
                                              int* __restrict__ chunkOff,
                                              int* __restrict__ bucketBase) {
  __shared__ int sb[512];
  int b = threadIdx.x;
  int s = 0;
  if (b < nb) {
    for (int c = 0; c < nchunks; ++c) {
      size_t idx = (size_t)c * nb + b;
      int v = chunkHist[idx];
      chunkOff[idx] = s;
      s += v;
    }
  }
  int tot = (b < nb) ? s : 0;
  int x = tot;
  sb[b] = x;
  __syncthreads();
  for (int off = 1; off < 512; off <<= 1) {
    int y = (b >= off) ? sb[b - off] : 0;
    __syncthreads();
    x += y;
    sb[b] = x;
    __syncthreads();
  }
  if (b < nb) bucketBase[b] = x - tot;  // exclusive
  if (b == 0) bucketBase[nb] = e;
}

// Counting-sort each chunk into bucket-major order; write packed entries to
// exact global slots (coalesced per bucket segment).
__global__ __launch_bounds__(256) void k_bin(const int* __restrict__ src,
                                             const int* __restrict__ dst, int e, int nb,
                                             const int* __restrict__ chunkHist,
                                             const int* __restrict__ chunkOff,
                                             const int* __restrict__ bucketBase,
                                             unsigned* __restrict__ binned) {
  __shared__ unsigned sortedL[CHUNK];
  __shared__ int gtarget[CHUNK];
  __shared__ int lbase[MAXB], lcur[MAXB], gbase[MAXB];
  int c = blockIdx.x;
  int base = c * CHUNK;
  int end = min(base + CHUNK, e);
  // stage this chunk's hist/offsets (already computed) + bucket bases
  for (int i = threadIdx.x; i < nb; i += 256) {
    lbase[i] = chunkHist[(size_t)c * nb + i];  // temp: counts
    gbase[i] = bucketBase[i] + chunkOff[(size_t)c * nb + i];
  }
  __syncthreads();
  if (threadIdx.x == 0) {  // serial exclusive scan of ~nb<=512 counts
    int s = 0;
    for (int i = 0; i < nb; ++i) {
      int v = lbase[i];
      lbase[i] = s;
      s += v;
    }
  }
  __syncthreads();
  for (int i = threadIdx.x; i < nb; i += 256) lcur[i] = lbase[i];
  __syncthreads();
  for (int i = base + threadIdx.x; i < end; i += 256) {
    int d = dst[i];
    int sv = src[i];
    int b = d >> BSHIFT;
    int slot = atomicAdd(&lcur[b], 1);
    sortedL[slot] = ((unsigned)sv << BSHIFT) | (unsigned)(d & BMASK);
    gtarget[slot] = gbase[b] + (slot - lbase[b]);
  }
  __syncthreads();
  for (int i = threadIdx.x; i < end - base; i += 256)
    binned[gtarget[i]] = sortedL[i];
}

// One block per bucket: build per-node CSR rows inside the bucket's private
// 16KB colIdx window (L2-resident, full-line merging). Also emits rowStart,
// deg, dis for all nodes -- replaces k_count/k_alloc entirely.
__global__ __launch_bounds__(256) void k_fill2(const unsigned* __restrict__ binned,
                                               const int* __restrict__ bucketBase, int n,
                                               int* __restrict__ rowStart,
                                               int* __restrict__ deg,
                                               float* __restrict__ dis,
                                               int* __restrict__ colIdx) {
  __shared__ int h[256], sb[256], cur[256];
  int b = blockIdx.x;
  int s0 = bucketBase[b], s1 = bucketBase[b + 1];
  int nodeBase = b << BSHIFT;
  int t = threadIdx.x;
  h[t] = 0;
  __syncthreads();
  for (int i = s0 + t; i < s1; i += 256) atomicAdd(&h[binned[i] & BMASK], 1);
  __syncthreads();
  int v = h[t];
  int x = v;
  sb[t] = x;
  __syncthreads();
  for (int off = 1; off < 256; off <<= 1) {
    int y = (t >= off) ? sb[t - off] : 0;
    __syncthreads();
    x += y;
    sb[t] = x;
    __syncthreads();
  }
  int start = s0 + x - v;  // exclusive within bucket + bucket base
  cur[t] = start;
  int node = nodeBase + t;
  if (node < n) {
    rowStart[node] = start;
    deg[node] = v;
    dis[node] = rsqrtf((float)(v + 1));  // +1 self-loop
  }
  __syncthreads();
  for (int i = s0 + t; i < s1; i += 256) {
    unsigned en = binned[i];
    int slot = atomicAdd(&cur[en & BMASK], 1);
    colIdx[slot] = (int)(en >> BSHIFT);
  }
}

// ---------------- dense matmul: O[n,128] = A[n,128] @ W[128,128] ----------------
// fp32 VALU (no fp32 MFMA on CDNA4). Full W (64 KB) in LDS. 64-row tile per
// block; thread tile 4 rows x 8 cols. A read straight from global (16 lanes
// share each address -> merges to one request; tile is L1/L2 resident) with
// one-chunk software prefetch. k-loop NOT unrolled (full unroll spilled:
// VGPR=256, WRITE_SIZE 438MB vs 51MB ideal).
__global__ __launch_bounds__(256) void k_matmul(const float* __restrict__ A,
                                                const float* __restrict__ W,
                                                float* __restrict__ O, int n) {
  __shared__ float Ws[FDIM * FDIM];  // 64 KB -> 2 blocks/CU
  int tid = threadIdx.x;
  for (int q = tid; q < FDIM * (FDIM / 4); q += 256) {
    int k = q >> 5, c = (q & 31) << 2;
    *(float4*)&Ws[k * FDIM + c] = *(const float4*)&W[k * FDIM + c];
  }
  __syncthreads();
  int tr = tid >> 4;         // 0..15
  int tc = (tid & 15) << 3;  // col base 0,8,...,120

  for (int r0 = blockIdx.x * 64; r0 < n; r0 += gridDim.x * 64) {
    int rbase = r0 + tr * 4;
    float acc[4][8];
#pragma unroll
    for (int r = 0; r < 4; ++r)
#pragma unroll
      for (int c = 0; c < 8; ++c) acc[r][c] = 0.f;

    float4 a_cur[4], a_nxt[4];
#pragma unroll
    for (int r = 0; r < 4; ++r)
      a_cur[r] = (rbase + r < n) ? *(const float4*)&A[(size_t)(rbase + r) * FDIM]
                                 : float4{0.f, 0.f, 0.f, 0.f};

#pragma unroll 1
    for (int k = 0; k < FDIM; k += 4) {
      if (k + 4 < FDIM) {
#pragma unroll
        for (int r = 0; r < 4; ++r)
          a_nxt[r] = (rbase + r < n)
                         ? *(const float4*)&A[(size_t)(rbase + r) * FDIM + k + 4]
                         : float4{0.f, 0.f, 0.f, 0.f};
      }
#pragma unroll
      for (int kk = 0; kk < 4; ++kk) {
        float4 w0 = *(const float4*)&Ws[(k + kk) * FDIM + tc];
        float4 w1 = *(const float4*)&Ws[(k + kk) * FDIM + tc + 4];
#pragma unroll
        for (int r = 0; r < 4; ++r) {
          float av = (&a_cur[r].x)[kk];
          acc[r][0] += av * w0.x;
          acc[r][1] += av * w0.y;
          acc[r][2] += av * w0.z;
          acc[r][3] += av * w0.w;
          acc[r][4] += av * w1.x;
          acc[r][5] += av * w1.y;
          acc[r][6] += av * w1.z;
          acc[r][7] += av * w1.w;
        }
      }
#pragma unroll
      for (int r = 0; r < 4; ++r) a_cur[r] = a_nxt[r];
    }

#pragma unroll
    for (int r = 0; r < 4; ++r) {
      if (rbase + r < n) {
        *(float4*)&O[(size_t)(rbase + r) * FDIM + tc] = *(float4*)&acc[r][0];
        *(float4*)&O[(size_t)(rbase + r) * FDIM + tc + 4] = *(float4*)&acc[r][4];
      }
    }
  }
}

// ---------------- aggregation (pull) + bias + ReLU ----------------
__global__ __launch_bounds__(256) void k_agg(const float* __restrict__ Hin,
                                             float* __restrict__ Hout,
                                             const int* __restrict__ rowStart,
                                             const int* __restrict__ degE,
                                             const int* __restrict__ colIdx,
                                             const float* __restrict__ dis,
                                             const float* __restrict__ bias, int n) {
  int node = blockIdx.x * 4 + (threadIdx.x >> 6);
  int lane = threadIdx.x & 63;
  if (node >= n) return;
  const float2* hin2 = (const float2*)Hin;
  float di = dis[node];
  float2 self = hin2[(size_t)node * 64 + lane];
  float ws = di * di;
  float ax = ws * self.x, ay = ws * self.y;
  int s0 = rowStart[node], cnt = degE[node];
#pragma unroll 4
  for (int j = 0; j < cnt; ++j) {
    int s = colIdx[s0 + j];
    float w = di * dis[s];
    float2 hv = hin2[(size_t)s * 64 + lane];
    ax += w * hv.x;
    ay += w * hv.y;
  }
  float2 b = ((const float2*)bias)[lane];
  ax = fmaxf(ax + b.x, 0.f);
  ay = fmaxf(ay + b.y, 0.f);
  float2 o;
  o.x = ax;
  o.y = ay;
  ((float2*)Hout)[(size_t)node * 64 + lane] = o;
}

// ---------------- pooling ----------------

__global__ __launch_bounds__(128) void k_gstart(const int* __restrict__ batch, int n,
                                                int g_count, int* __restrict__ gstart) {
  int g = threadIdx.x;
  if (g > g_count) return;
  int lo = 0, hi = n;
  while (lo < hi) {
    int mid = (lo + hi) >> 1;
    if (batch[mid] < g) lo = mid + 1;
    else hi = mid;
  }
  gstart[g] = lo;
}

__global__ __launch_bounds__(128) void k_pool(const float* __restrict__ H,
                                              const int* __restrict__ gstart,
                                              float* __restrict__ pooled, int g_count) {
  int g = blockIdx.x >> 4;
  int c = blockIdx.x & 15;
  int s = gstart[g], e = gstart[g + 1];
  int len = e - s;
  int chunk = (len + 15) >> 4;
  int ns = s + c * chunk;
  int ne = min(ns + chunk, e);
  float acc = 0.f;
  for (int i = ns; i < ne; ++i) acc += H[(size_t)i * FDIM + threadIdx.x];
  atomicAdd(&pooled[g * FDIM + threadIdx.x], acc);
}

__global__ __launch_bounds__(192) void k_final(const float* __restrict__ pooled,
                                               const int* __restrict__ gstart,
                                               const float* __restrict__ Wc,
                                               const float* __restrict__ bc,
                                               float* __restrict__ out, int g_count) {
  int t = threadIdx.x;
  if (t >= g_count * 3) return;
  int g = t / 3, c = t % 3;
  int cnt = gstart[g + 1] - gstart[g];
  float inv = 1.0f / (float)max(cnt, 1);
  float acc = bc[c];
#pragma unroll 8
  for (int k = 0; k < FDIM; ++k) acc += pooled[g * FDIM + k] * inv * Wc[k * 3 + c];
  out[g * 3 + c] = acc;
}

// ---------------- host ----------------

extern "C" void kernel_launch(void* const* d_in, const int* in_sizes, int n_in,
                              void* d_out, int out_size, void* d_ws, size_t ws_size,
                              hipStream_t stream) {
  const float* x = (const float*)d_in[0];
  const int* edge = (const int*)d_in[1];
  const int* batch = (const int*)d_in[2];
  const float* W1 = (const float*)d_in[3];
  const float* b1 = (const float*)d_in[4];
  const float* W2 = (const float*)d_in[5];
  const float* b2 = (const float*)d_in[6];
  const float* W3 = (const float*)d_in[7];
  const float* b3 = (const float*)d_in[8];
  const float* Wc = (const float*)d_in[9];
  const float* bc = (const float*)d_in[10];
  float* out = (float*)d_out;

  const int N = in_sizes[0] / FDIM;
  const int E = in_sizes[1] / 2;
  const int G = out_size / 3;
  const int* src = edge;
  const int* dst = edge + E;

  const int NCH = (E + CHUNK - 1) / CHUNK;      // chunks
  const int NB = (N + (1 << BSHIFT) - 1) >> BSHIFT;  // buckets (<= MAXB)

  char* ws = (char*)d_ws;
  size_t off = 0;
  auto carve = [&](size_t bytes) -> void* {
    void* p = ws + off;
    off = (off + bytes + 255) & ~(size_t)255;
    return p;
  };
  float* h0 = (float*)carve((size_t)N * FDIM * 4);
  float* h1 = (float*)carve((size_t)N * FDIM * 4);
  int* colIdx = (int*)carve((size_t)E * 4);
  unsigned* binned = (unsigned*)carve((size_t)E * 4);
  int* chunkHist = (int*)carve((size_t)NCH * NB * 4);
  int* chunkOff = (int*)carve((size_t)NCH * NB * 4);
  int* bucketBase = (int*)carve((size_t)(NB + 1) * 4);
  int* rowStart = (int*)carve((size_t)N * 4);
  int* deg = (int*)carve((size_t)N * 4);
  float* dis = (float*)carve((size_t)N * 4);
  int* gstart = (int*)carve((size_t)(G + 1) * 4);
  float* pooled = (float*)carve((size_t)G * FDIM * 4);
  (void)n_in;
  (void)ws_size;

  hipMemsetAsync(pooled, 0, (size_t)G * FDIM * 4, stream);

  k_hist<<<NCH, 256, 0, stream>>>(dst, E, NB, chunkHist);
  k_scan<<<1, 512, 0, stream>>>(chunkHist, NCH, NB, E, chunkOff, bucketBase);
  k_bin<<<NCH, 256, 0, stream>>>(src, dst, E, NB, chunkHist, chunkOff, bucketBase,
                                 binned);
  k_fill2<<<NB, 256, 0, stream>>>(binned, bucketBase, N, rowStart, deg, dis, colIdx);

  int mmb = (N + 63) / 64;
  k_matmul<<<mmb, 256, 0, stream>>>(x, W1, h0, N);
  k_agg<<<(N + 3) / 4, 256, 0, stream>>>(h0, h1, rowStart, deg, colIdx, dis, b1, N);
  k_matmul<<<mmb, 256, 0, stream>>>(h1, W2, h0, N);
  k_agg<<<(N + 3) / 4, 256, 0, stream>>>(h0, h1, rowStart, deg, colIdx, dis, b2, N);
  k_matmul<<<mmb, 256, 0, stream>>>(h1, W3, h0, N);
  k_agg<<<(N + 3) / 4, 256, 0, stream>>>(h0, h1, rowStart, deg, colIdx, dis, b3, N);

  k_gstart<<<1, 128, 0, stream>>>(batch, N, G, gstart);
  k_pool<<<G * 16, 128, 0, stream>>>(h1, gstart, pooled, G);
  k_final<<<1, 192, 0, stream>>>(pooled, gstart, Wc, bc, out, G);
}

// Round 4
// 785.531 us; speedup vs baseline: 1.9780x; 1.1184x over previous
//
#include <hip/hip_runtime.h>
#include <cstdint>
#include <cstddef>

#define FDIM 128
#define CHUNK 4096   // edges per binning chunk
#define BSHIFT 8     // 256 nodes per bucket
#define BMASK 255
#define MAXB 512     // max buckets supported (N <= 131072)

typedef unsigned short ushort_t;

// bf16 helpers (bit-level, RTN-even) -- avoids header/type quirks.
__device__ inline ushort_t f2bf(float f) {
  unsigned u = __float_as_uint(f);
  u += 0x7fffu + ((u >> 16) & 1u);
  return (ushort_t)(u >> 16);
}
__device__ inline float bf2f(ushort_t h) {
  return __uint_as_float((unsigned)h << 16);
}

// ---------------- CSR build (bucketed) ----------------

__global__ __launch_bounds__(256) void k_hist(const int* __restrict__ dst, int e,
                                              int nb, int* __restrict__ chunkHist) {
  __shared__ int h[MAXB];
  int c = blockIdx.x;
  int base = c * CHUNK;
  int end = min(base + CHUNK, e);
  for (int i = threadIdx.x; i < nb; i += 256) h[i] = 0;
  __syncthreads();
  for (int i = base + threadIdx.x; i < end; i += 256)
    atomicAdd(&h[dst[i] >> BSHIFT], 1);
  __syncthreads();
  for (int b = threadIdx.x; b < nb; b += 256)
    chunkHist[(size_t)c * nb + b] = h[b];
}

__global__ __launch_bounds__(512) void k_scan(const int* __restrict__ chunkHist,
                                              int nchunks, int nb, int e,
                                              int* __restrict__ chunkOff,
                                              int* __restrict__ bucketBase) {
  __shared__ int sb[512];
  int b = threadIdx.x;
  int s = 0;
  if (b < nb) {
    for (int c = 0; c < nchunks; ++c) {
      size_t idx = (size_t)c * nb + b;
      int v = chunkHist[idx];
      chunkOff[idx] = s;
      s += v;
    }
  }
  int tot = (b < nb) ? s : 0;
  int x = tot;
  sb[b] = x;
  __syncthreads();
  for (int off = 1; off < 512; off <<= 1) {
    int y = (b >= off) ? sb[b - off] : 0;
    __syncthreads();
    x += y;
    sb[b] = x;
    __syncthreads();
  }
  if (b < nb) bucketBase[b] = x - tot;  // exclusive
  if (b == 0) bucketBase[nb] = e;
}

__global__ __launch_bounds__(256) void k_bin(const int* __restrict__ src,
                                             const int* __restrict__ dst, int e, int nb,
                                             const int* __restrict__ chunkHist,
                                             const int* __restrict__ chunkOff,
                                             const int* __restrict__ bucketBase,
                                             unsigned* __restrict__ binned) {
  __shared__ unsigned sortedL[CHUNK];
  __shared__ int gtarget[CHUNK];
  __shared__ int lbase[MAXB], lcur[MAXB], gbase[MAXB];
  int c = blockIdx.x;
  int base = c * CHUNK;
  int end = min(base + CHUNK, e);
  for (int i = threadIdx.x; i < nb; i += 256) {
    lbase[i] = chunkHist[(size_t)c * nb + i];  // temp: counts
    gbase[i] = bucketBase[i] + chunkOff[(size_t)c * nb + i];
  }
  __syncthreads();
  if (threadIdx.x == 0) {
    int s = 0;
    for (int i = 0; i < nb; ++i) {
      int v = lbase[i];
      lbase[i] = s;
      s += v;
    }
  }
  __syncthreads();
  for (int i = threadIdx.x; i < nb; i += 256) lcur[i] = lbase[i];
  __syncthreads();
  for (int i = base + threadIdx.x; i < end; i += 256) {
    int d = dst[i];
    int sv = src[i];
    int b = d >> BSHIFT;
    int slot = atomicAdd(&lcur[b], 1);
    sortedL[slot] = ((unsigned)sv << BSHIFT) | (unsigned)(d & BMASK);
    gtarget[slot] = gbase[b] + (slot - lbase[b]);
  }
  __syncthreads();
  for (int i = threadIdx.x; i < end - base; i += 256)
    binned[gtarget[i]] = sortedL[i];
}

__global__ __launch_bounds__(256) void k_fill2(const unsigned* __restrict__ binned,
                                               const int* __restrict__ bucketBase, int n,
                                               int* __restrict__ rowStart,
                                               int* __restrict__ deg,
                                               float* __restrict__ dis,
                                               int* __restrict__ colIdx) {
  __shared__ int h[256], sb[256], cur[256];
  int b = blockIdx.x;
  int s0 = bucketBase[b], s1 = bucketBase[b + 1];
  int nodeBase = b << BSHIFT;
  int t = threadIdx.x;
  h[t] = 0;
  __syncthreads();
  for (int i = s0 + t; i < s1; i += 256) atomicAdd(&h[binned[i] & BMASK], 1);
  __syncthreads();
  int v = h[t];
  int x = v;
  sb[t] = x;
  __syncthreads();
  for (int off = 1; off < 256; off <<= 1) {
    int y = (t >= off) ? sb[t - off] : 0;
    __syncthreads();
    x += y;
    sb[t] = x;
    __syncthreads();
  }
  int start = s0 + x - v;
  cur[t] = start;
  int node = nodeBase + t;
  if (node < n) {
    rowStart[node] = start;
    deg[node] = v;
    dis[node] = rsqrtf((float)(v + 1));  // +1 self-loop
  }
  __syncthreads();
  for (int i = s0 + t; i < s1; i += 256) {
    unsigned en = binned[i];
    int slot = atomicAdd(&cur[en & BMASK], 1);
    colIdx[slot] = (int)(en >> BSHIFT);
  }
}

// ---------------- dense matmul: O[n,128] = A[n,128] @ W[128,128] ----------------
// fp32 VALU math (no fp32 MFMA on CDNA4), W fp32 in LDS (64 KB), thread tile
// 4x8, software prefetch, k-loop NOT unrolled (full unroll spilled to 256
// VGPR + 438MB scratch writes in round 1). A input is fp32 (layer 1) or bf16
// (layers 2,3); output bf16 (halves the downstream gather bytes).
template <int INBF>
__global__ __launch_bounds__(256) void k_matmul(const void* __restrict__ Ain,
                                                const float* __restrict__ W,
                                                ushort_t* __restrict__ O, int n) {
  __shared__ float Ws[FDIM * FDIM];  // 64 KB
  int tid = threadIdx.x;
  for (int q = tid; q < FDIM * (FDIM / 4); q += 256) {
    int k = q >> 5, c = (q & 31) << 2;
    *(float4*)&Ws[k * FDIM + c] = *(const float4*)&W[k * FDIM + c];
  }
  __syncthreads();
  int tr = tid >> 4;         // 0..15
  int tc = (tid & 15) << 3;  // col base 0,8,...,120
  const float* Af = (const float*)Ain;
  const ushort_t* Ab = (const ushort_t*)Ain;

  for (int r0 = blockIdx.x * 64; r0 < n; r0 += gridDim.x * 64) {
    int rbase = r0 + tr * 4;
    float acc[4][8];
#pragma unroll
    for (int r = 0; r < 4; ++r)
#pragma unroll
      for (int c = 0; c < 8; ++c) acc[r][c] = 0.f;

    float4 a_cur[4], a_nxt[4];
#pragma unroll
    for (int r = 0; r < 4; ++r) {
      if (rbase + r < n) {
        if (INBF) {
          ushort4 u = *(const ushort4*)&Ab[(size_t)(rbase + r) * FDIM];
          a_cur[r] = float4{bf2f(u.x), bf2f(u.y), bf2f(u.z), bf2f(u.w)};
        } else {
          a_cur[r] = *(const float4*)&Af[(size_t)(rbase + r) * FDIM];
        }
      } else
        a_cur[r] = float4{0.f, 0.f, 0.f, 0.f};
    }

#pragma unroll 1
    for (int k = 0; k < FDIM; k += 4) {
      if (k + 4 < FDIM) {
#pragma unroll
        for (int r = 0; r < 4; ++r) {
          if (rbase + r < n) {
            if (INBF) {
              ushort4 u = *(const ushort4*)&Ab[(size_t)(rbase + r) * FDIM + k + 4];
              a_nxt[r] = float4{bf2f(u.x), bf2f(u.y), bf2f(u.z), bf2f(u.w)};
            } else {
              a_nxt[r] = *(const float4*)&Af[(size_t)(rbase + r) * FDIM + k + 4];
            }
          } else
            a_nxt[r] = float4{0.f, 0.f, 0.f, 0.f};
        }
      }
#pragma unroll
      for (int kk = 0; kk < 4; ++kk) {
        float4 w0 = *(const float4*)&Ws[(k + kk) * FDIM + tc];
        float4 w1 = *(const float4*)&Ws[(k + kk) * FDIM + tc + 4];
#pragma unroll
        for (int r = 0; r < 4; ++r) {
          float av = (&a_cur[r].x)[kk];
          acc[r][0] += av * w0.x;
          acc[r][1] += av * w0.y;
          acc[r][2] += av * w0.z;
          acc[r][3] += av * w0.w;
          acc[r][4] += av * w1.x;
          acc[r][5] += av * w1.y;
          acc[r][6] += av * w1.z;
          acc[r][7] += av * w1.w;
        }
      }
#pragma unroll
      for (int r = 0; r < 4; ++r) a_cur[r] = a_nxt[r];
    }

#pragma unroll
    for (int r = 0; r < 4; ++r) {
      if (rbase + r < n) {
        ushort4 o0{f2bf(acc[r][0]), f2bf(acc[r][1]), f2bf(acc[r][2]), f2bf(acc[r][3])};
        ushort4 o1{f2bf(acc[r][4]), f2bf(acc[r][5]), f2bf(acc[r][6]), f2bf(acc[r][7])};
        *(ushort4*)&O[(size_t)(rbase + r) * FDIM + tc] = o0;
        *(ushort4*)&O[(size_t)(rbase + r) * FDIM + tc + 4] = o1;
      }
    }
  }
}

// ---------------- aggregation (pull) + bias + ReLU, bf16 H ----------------
// One wave per node, lane handles 2 features (one packed uint). Gathered row
// = 256 B contiguous (4 lines). Math in fp32, store bf16.
__global__ __launch_bounds__(256) void k_agg(const ushort_t* __restrict__ Hin,
                                             ushort_t* __restrict__ Hout,
                                             const int* __restrict__ rowStart,
                                             const int* __restrict__ degE,
                                             const int* __restrict__ colIdx,
                                             const float* __restrict__ dis,
                                             const float* __restrict__ bias, int n) {
  int node = blockIdx.x * 4 + (threadIdx.x >> 6);
  int lane = threadIdx.x & 63;
  if (node >= n) return;
  const unsigned* hin = (const unsigned*)Hin;  // row stride 64 uints
  float di = dis[node];
  unsigned us = hin[(size_t)node * 64 + lane];
  float ws = di * di;
  float ax = ws * __uint_as_float(us << 16);
  float ay = ws * __uint_as_float(us & 0xffff0000u);
  int s0 = rowStart[node], cnt = degE[node];
#pragma unroll 4
  for (int j = 0; j < cnt; ++j) {
    int s = colIdx[s0 + j];
    float w = di * dis[s];
    unsigned u = hin[(size_t)s * 64 + lane];
    ax += w * __uint_as_float(u << 16);
    ay += w * __uint_as_float(u & 0xffff0000u);
  }
  float2 b = ((const float2*)bias)[lane];
  ax = fmaxf(ax + b.x, 0.f);
  ay = fmaxf(ay + b.y, 0.f);
  unsigned out = (unsigned)f2bf(ax) | ((unsigned)f2bf(ay) << 16);
  ((unsigned*)Hout)[(size_t)node * 64 + lane] = out;
}

// ---------------- pooling ----------------

__global__ __launch_bounds__(128) void k_gstart(const int* __restrict__ batch, int n,
                                                int g_count, int* __restrict__ gstart) {
  int g = threadIdx.x;
  if (g > g_count) return;
  int lo = 0, hi = n;
  while (lo < hi) {
    int mid = (lo + hi) >> 1;
    if (batch[mid] < g) lo = mid + 1;
    else hi = mid;
  }
  gstart[g] = lo;
}

__global__ __launch_bounds__(128) void k_pool(const ushort_t* __restrict__ H,
                                              const int* __restrict__ gstart,
                                              float* __restrict__ pooled, int g_count) {
  int g = blockIdx.x >> 4;
  int c = blockIdx.x & 15;
  int s = gstart[g], e = gstart[g + 1];
  int len = e - s;
  int chunk = (len + 15) >> 4;
  int ns = s + c * chunk;
  int ne = min(ns + chunk, e);
  float acc = 0.f;
  for (int i = ns; i < ne; ++i) acc += bf2f(H[(size_t)i * FDIM + threadIdx.x]);
  atomicAdd(&pooled[g * FDIM + threadIdx.x], acc);
}

__global__ __launch_bounds__(192) void k_final(const float* __restrict__ pooled,
                                               const int* __restrict__ gstart,
                                               const float* __restrict__ Wc,
                                               const float* __restrict__ bc,
                                               float* __restrict__ out, int g_count) {
  int t = threadIdx.x;
  if (t >= g_count * 3) return;
  int g = t / 3, c = t % 3;
  int cnt = gstart[g + 1] - gstart[g];
  float inv = 1.0f / (float)max(cnt, 1);
  float acc = bc[c];
#pragma unroll 8
  for (int k = 0; k < FDIM; ++k) acc += pooled[g * FDIM + k] * inv * Wc[k * 3 + c];
  out[g * 3 + c] = acc;
}

// ---------------- host ----------------

extern "C" void kernel_launch(void* const* d_in, const int* in_sizes, int n_in,
                              void* d_out, int out_size, void* d_ws, size_t ws_size,
                              hipStream_t stream) {
  const float* x = (const float*)d_in[0];
  const int* edge = (const int*)d_in[1];
  const int* batch = (const int*)d_in[2];
  const float* W1 = (const float*)d_in[3];
  const float* b1 = (const float*)d_in[4];
  const float* W2 = (const float*)d_in[5];
  const float* b2 = (const float*)d_in[6];
  const float* W3 = (const float*)d_in[7];
  const float* b3 = (const float*)d_in[8];
  const float* Wc = (const float*)d_in[9];
  const float* bc = (const float*)d_in[10];
  float* out = (float*)d_out;

  const int N = in_sizes[0] / FDIM;
  const int E = in_sizes[1] / 2;
  const int G = out_size / 3;
  const int* src = edge;
  const int* dst = edge + E;

  const int NCH = (E + CHUNK - 1) / CHUNK;
  const int NB = (N + (1 << BSHIFT) - 1) >> BSHIFT;

  char* ws = (char*)d_ws;
  size_t off = 0;
  auto carve = [&](size_t bytes) -> void* {
    void* p = ws + off;
    off = (off + bytes + 255) & ~(size_t)255;
    return p;
  };
  ushort_t* h0 = (ushort_t*)carve((size_t)N * FDIM * 2);  // bf16 activations
  ushort_t* h1 = (ushort_t*)carve((size_t)N * FDIM * 2);
  int* colIdx = (int*)carve((size_t)E * 4);
  unsigned* binned = (unsigned*)carve((size_t)E * 4);
  int* chunkHist = (int*)carve((size_t)NCH * NB * 4);
  int* chunkOff = (int*)carve((size_t)NCH * NB * 4);
  int* bucketBase = (int*)carve((size_t)(NB + 1) * 4);
  int* rowStart = (int*)carve((size_t)N * 4);
  int* deg = (int*)carve((size_t)N * 4);
  float* dis = (float*)carve((size_t)N * 4);
  int* gstart = (int*)carve((size_t)(G + 1) * 4);
  float* pooled = (float*)carve((size_t)G * FDIM * 4);
  (void)n_in;
  (void)ws_size;

  hipMemsetAsync(pooled, 0, (size_t)G * FDIM * 4, stream);

  k_hist<<<NCH, 256, 0, stream>>>(dst, E, NB, chunkHist);
  k_scan<<<1, 512, 0, stream>>>(chunkHist, NCH, NB, E, chunkOff, bucketBase);
  k_bin<<<NCH, 256, 0, stream>>>(src, dst, E, NB, chunkHist, chunkOff, bucketBase,
                                 binned);
  k_fill2<<<NB, 256, 0, stream>>>(binned, bucketBase, N, rowStart, deg, dis, colIdx);

  int mmb = (N + 63) / 64;
  k_matmul<0><<<mmb, 256, 0, stream>>>(x, W1, h0, N);
  k_agg<<<(N + 3) / 4, 256, 0, stream>>>(h0, h1, rowStart, deg, colIdx, dis, b1, N);
  k_matmul<1><<<mmb, 256, 0, stream>>>(h1, W2, h0, N);
  k_agg<<<(N + 3) / 4, 256, 0, stream>>>(h0, h1, rowStart, deg, colIdx, dis, b2, N);
  k_matmul<1><<<mmb, 256, 0, stream>>>(h1, W3, h0, N);
  k_agg<<<(N + 3) / 4, 256, 0, stream>>>(h0, h1, rowStart, deg, colIdx, dis, b3, N);

  k_gstart<<<1, 128, 0, stream>>>(batch, N, G, gstart);
  k_pool<<<G * 16, 128, 0, stream>>>(h1, gstart, pooled, G);
  k_final<<<1, 192, 0, stream>>>(pooled, gstart, Wc, bc, out, G);
}

// Round 5
// 592.869 us; speedup vs baseline: 2.6207x; 1.3250x over previous
//
#include <hip/hip_runtime.h>
#include <cstdint>
#include <cstddef>

#define FDIM 128
#define CHUNK 4096   // edges per binning chunk
#define BSHIFT 8     // 256 nodes per bucket
#define BMASK 255
#define MAXB 512     // max buckets supported (N <= 131072)

typedef unsigned short ushort_t;
typedef __attribute__((ext_vector_type(8))) short short8;   // 8 bf16 (4 VGPRs)
typedef __attribute__((ext_vector_type(4))) float floatx4;  // MFMA C/D

// bf16 helpers (bit-level, RTN-even).
__device__ inline ushort_t f2bf(float f) {
  unsigned u = __float_as_uint(f);
  u += 0x7fffu + ((u >> 16) & 1u);
  return (ushort_t)(u >> 16);
}
__device__ inline float bf2f(ushort_t h) {
  return __uint_as_float((unsigned)h << 16);
}

// ---------------- CSR build (bucketed) ----------------

__global__ __launch_bounds__(256) void k_hist(const int* __restrict__ dst, int e,
                                              int nb, int* __restrict__ chunkHist) {
  __shared__ int h[MAXB];
  int c = blockIdx.x;
  int base = c * CHUNK;
  int end = min(base + CHUNK, e);
  for (int i = threadIdx.x; i < nb; i += 256) h[i] = 0;
  __syncthreads();
  for (int i = base + threadIdx.x; i < end; i += 256)
    atomicAdd(&h[dst[i] >> BSHIFT], 1);
  __syncthreads();
  for (int b = threadIdx.x; b < nb; b += 256)
    chunkHist[(size_t)c * nb + b] = h[b];
}

__global__ __launch_bounds__(512) void k_scan(const int* __restrict__ chunkHist,
                                              int nchunks, int nb, int e,
                                              int* __restrict__ chunkOff,
                                              int* __restrict__ bucketBase) {
  __shared__ int sb[512];
  int b = threadIdx.x;
  int s = 0;
  if (b < nb) {
    for (int c = 0; c < nchunks; ++c) {
      size_t idx = (size_t)c * nb + b;
      int v = chunkHist[idx];
      chunkOff[idx] = s;
      s += v;
    }
  }
  int tot = (b < nb) ? s : 0;
  int x = tot;
  sb[b] = x;
  __syncthreads();
  for (int off = 1; off < 512; off <<= 1) {
    int y = (b >= off) ? sb[b - off] : 0;
    __syncthreads();
    x += y;
    sb[b] = x;
    __syncthreads();
  }
  if (b < nb) bucketBase[b] = x - tot;  // exclusive
  if (b == 0) bucketBase[nb] = e;
}

__global__ __launch_bounds__(256) void k_bin(const int* __restrict__ src,
                                             const int* __restrict__ dst, int e, int nb,
                                             const int* __restrict__ chunkHist,
                                             const int* __restrict__ chunkOff,
                                             const int* __restrict__ bucketBase,
                                             unsigned* __restrict__ binned) {
  __shared__ unsigned sortedL[CHUNK];
  __shared__ int gtarget[CHUNK];
  __shared__ int lbase[MAXB], lcur[MAXB], gbase[MAXB];
  int c = blockIdx.x;
  int base = c * CHUNK;
  int end = min(base + CHUNK, e);
  for (int i = threadIdx.x; i < nb; i += 256) {
    lbase[i] = chunkHist[(size_t)c * nb + i];  // temp: counts
    gbase[i] = bucketBase[i] + chunkOff[(size_t)c * nb + i];
  }
  __syncthreads();
  if (threadIdx.x == 0) {
    int s = 0;
    for (int i = 0; i < nb; ++i) {
      int v = lbase[i];
      lbase[i] = s;
      s += v;
    }
  }
  __syncthreads();
  for (int i = threadIdx.x; i < nb; i += 256) lcur[i] = lbase[i];
  __syncthreads();
  for (int i = base + threadIdx.x; i < end; i += 256) {
    int d = dst[i];
    int sv = src[i];
    int b = d >> BSHIFT;
    int slot = atomicAdd(&lcur[b], 1);
    sortedL[slot] = ((unsigned)sv << BSHIFT) | (unsigned)(d & BMASK);
    gtarget[slot] = gbase[b] + (slot - lbase[b]);
  }
  __syncthreads();
  for (int i = threadIdx.x; i < end - base; i += 256)
    binned[gtarget[i]] = sortedL[i];
}

__global__ __launch_bounds__(256) void k_fill2(const unsigned* __restrict__ binned,
                                               const int* __restrict__ bucketBase, int n,
                                               int* __restrict__ rowStart,
                                               int* __restrict__ deg,
                                               float* __restrict__ dis,
                                               int* __restrict__ colIdx) {
  __shared__ int h[256], sb[256], cur[256];
  int b = blockIdx.x;
  int s0 = bucketBase[b], s1 = bucketBase[b + 1];
  int nodeBase = b << BSHIFT;
  int t = threadIdx.x;
  h[t] = 0;
  __syncthreads();
  for (int i = s0 + t; i < s1; i += 256) atomicAdd(&h[binned[i] & BMASK], 1);
  __syncthreads();
  int v = h[t];
  int x = v;
  sb[t] = x;
  __syncthreads();
  for (int off = 1; off < 256; off <<= 1) {
    int y = (t >= off) ? sb[t - off] : 0;
    __syncthreads();
    x += y;
    sb[t] = x;
    __syncthreads();
  }
  int start = s0 + x - v;
  cur[t] = start;
  int node = nodeBase + t;
  if (node < n) {
    rowStart[node] = start;
    deg[node] = v;
    dis[node] = rsqrtf((float)(v + 1));  // +1 self-loop
  }
  __syncthreads();
  for (int i = s0 + t; i < s1; i += 256) {
    unsigned en = binned[i];
    int slot = atomicAdd(&cur[en & BMASK], 1);
    colIdx[slot] = (int)(en >> BSHIFT);
  }
}

// ---------------- W prep: fp32 -> bf16, swizzled into B-fragment order ----
// For mfma_f32_16x16x32_bf16, B fragment: lane holds B[k = (lane>>4)*8 + j]
// [n = lane&15], j=0..7 contiguous. Store Wsw[((kc*8+ct)*64+lane)*8+j] =
// bf16(W[kc*32 + (lane>>4)*8 + j][ct*16 + (lane&15)]), so each lane's frag
// is ONE 16B LDS read, conflict-free (16B/lane stride).
__global__ __launch_bounds__(256) void k_prepw(const float* __restrict__ W1,
                                               const float* __restrict__ W2,
                                               const float* __restrict__ W3,
                                               ushort_t* __restrict__ out) {
  int b = blockIdx.x;
  const float* W = (b == 0) ? W1 : (b == 1) ? W2 : W3;
  ushort_t* o = out + (size_t)b * 16384;
  for (int idx = threadIdx.x; idx < 16384; idx += 256) {
    int j = idx & 7;
    int lane = (idx >> 3) & 63;
    int ct = (idx >> 9) & 7;
    int kc = idx >> 12;
    int k = kc * 32 + (lane >> 4) * 8 + j;
    int col = ct * 16 + (lane & 15);
    o[idx] = f2bf(W[k * FDIM + col]);
  }
}

// ---------------- MFMA matmul: O[n,128] = A[n,128] @ W[128,128] ----------------
// bf16 inputs, fp32 accumulate. Block = 4 waves x 32 rows = 128 rows.
// A-frag: lane reads A[rb + rt*16 + (lane&15)][kc*32 + (lane>>4)*8 .. +7]
// = one 16B global load. B-frags from LDS (pre-swizzled). 2x8 acc tiles.
template <int INBF>
__global__ __launch_bounds__(256) void k_mm(const void* __restrict__ Ain,
                                            const ushort_t* __restrict__ Wsw,
                                            ushort_t* __restrict__ O, int n) {
  __shared__ ushort_t Bs[16384];  // 32 KB
  int tid = threadIdx.x;
  for (int q = tid; q < 2048; q += 256)
    ((uint4*)Bs)[q] = ((const uint4*)Wsw)[q];
  __syncthreads();

  int w = tid >> 6;
  int lane = tid & 63;
  int quad = lane >> 4;
  int l15 = lane & 15;
  int rb = blockIdx.x * 128 + w * 32;
  const float* Af = (const float*)Ain;
  const ushort_t* Ab = (const ushort_t*)Ain;

  int row0 = rb + l15;        // rt=0 A-row
  int row1 = rb + 16 + l15;   // rt=1 A-row
  bool v0 = row0 < n, v1 = row1 < n;

  floatx4 acc[2][8];
#pragma unroll
  for (int rt = 0; rt < 2; ++rt)
#pragma unroll
    for (int ct = 0; ct < 8; ++ct) acc[rt][ct] = floatx4{0.f, 0.f, 0.f, 0.f};

#pragma unroll
  for (int kc = 0; kc < 4; ++kc) {
    int k0 = kc * 32 + quad * 8;
    short8 a0 = short8{0, 0, 0, 0, 0, 0, 0, 0};
    short8 a1 = short8{0, 0, 0, 0, 0, 0, 0, 0};
    if (INBF) {
      if (v0) a0 = *(const short8*)&Ab[(size_t)row0 * FDIM + k0];
      if (v1) a1 = *(const short8*)&Ab[(size_t)row1 * FDIM + k0];
    } else {
      if (v0) {
        float4 f0 = *(const float4*)&Af[(size_t)row0 * FDIM + k0];
        float4 f1 = *(const float4*)&Af[(size_t)row0 * FDIM + k0 + 4];
        a0 = short8{(short)f2bf(f0.x), (short)f2bf(f0.y), (short)f2bf(f0.z),
                    (short)f2bf(f0.w), (short)f2bf(f1.x), (short)f2bf(f1.y),
                    (short)f2bf(f1.z), (short)f2bf(f1.w)};
      }
      if (v1) {
        float4 f0 = *(const float4*)&Af[(size_t)row1 * FDIM + k0];
        float4 f1 = *(const float4*)&Af[(size_t)row1 * FDIM + k0 + 4];
        a1 = short8{(short)f2bf(f0.x), (short)f2bf(f0.y), (short)f2bf(f0.z),
                    (short)f2bf(f0.w), (short)f2bf(f1.x), (short)f2bf(f1.y),
                    (short)f2bf(f1.z), (short)f2bf(f1.w)};
      }
    }
#pragma unroll
    for (int ct = 0; ct < 8; ++ct) {
      short8 bf = *(const short8*)&Bs[((kc * 8 + ct) * 64 + lane) * 8];
      acc[0][ct] = __builtin_amdgcn_mfma_f32_16x16x32_bf16(a0, bf, acc[0][ct], 0, 0, 0);
      acc[1][ct] = __builtin_amdgcn_mfma_f32_16x16x32_bf16(a1, bf, acc[1][ct], 0, 0, 0);
    }
  }

  // C/D layout: col = lane&15, row = quad*4 + i  (within 16x16 tile)
#pragma unroll
  for (int rt = 0; rt < 2; ++rt) {
#pragma unroll
    for (int i = 0; i < 4; ++i) {
      int row = rb + rt * 16 + quad * 4 + i;
      if (row < n) {
#pragma unroll
        for (int ct = 0; ct < 8; ++ct)
          O[(size_t)row * FDIM + ct * 16 + l15] = f2bf(acc[rt][ct][i]);
      }
    }
  }
}

// ---------------- aggregation (pull) + bias + ReLU, bf16 H ----------------
__global__ __launch_bounds__(256) void k_agg(const ushort_t* __restrict__ Hin,
                                             ushort_t* __restrict__ Hout,
                                             const int* __restrict__ rowStart,
                                             const int* __restrict__ degE,
                                             const int* __restrict__ colIdx,
                                             const float* __restrict__ dis,
                                             const float* __restrict__ bias, int n) {
  int node = blockIdx.x * 4 + (threadIdx.x >> 6);
  int lane = threadIdx.x & 63;
  if (node >= n) return;
  const unsigned* hin = (const unsigned*)Hin;  // row stride 64 uints
  float di = dis[node];
  unsigned us = hin[(size_t)node * 64 + lane];
  float ws = di * di;
  float ax = ws * __uint_as_float(us << 16);
  float ay = ws * __uint_as_float(us & 0xffff0000u);
  int s0 = rowStart[node], cnt = degE[node];
#pragma unroll 4
  for (int j = 0; j < cnt; ++j) {
    int s = colIdx[s0 + j];
    float w = di * dis[s];
    unsigned u = hin[(size_t)s * 64 + lane];
    ax += w * __uint_as_float(u << 16);
    ay += w * __uint_as_float(u & 0xffff0000u);
  }
  float2 b = ((const float2*)bias)[lane];
  ax = fmaxf(ax + b.x, 0.f);
  ay = fmaxf(ay + b.y, 0.f);
  unsigned out = (unsigned)f2bf(ax) | ((unsigned)f2bf(ay) << 16);
  ((unsigned*)Hout)[(size_t)node * 64 + lane] = out;
}

// ---------------- pooling ----------------

__global__ __launch_bounds__(128) void k_gstart(const int* __restrict__ batch, int n,
                                                int g_count, int* __restrict__ gstart) {
  int g = threadIdx.x;
  if (g > g_count) return;
  int lo = 0, hi = n;
  while (lo < hi) {
    int mid = (lo + hi) >> 1;
    if (batch[mid] < g) lo = mid + 1;
    else hi = mid;
  }
  gstart[g] = lo;
}

__global__ __launch_bounds__(128) void k_pool(const ushort_t* __restrict__ H,
                                              const int* __restrict__ gstart,
                                              float* __restrict__ pooled, int g_count) {
  int g = blockIdx.x >> 4;
  int c = blockIdx.x & 15;
  int s = gstart[g], e = gstart[g + 1];
  int len = e - s;
  int chunk = (len + 15) >> 4;
  int ns = s + c * chunk;
  int ne = min(ns + chunk, e);
  float acc = 0.f;
  for (int i = ns; i < ne; ++i) acc += bf2f(H[(size_t)i * FDIM + threadIdx.x]);
  atomicAdd(&pooled[g * FDIM + threadIdx.x], acc);
}

__global__ __launch_bounds__(192) void k_final(const float* __restrict__ pooled,
                                               const int* __restrict__ gstart,
                                               const float* __restrict__ Wc,
                                               const float* __restrict__ bc,
                                               float* __restrict__ out, int g_count) {
  int t = threadIdx.x;
  if (t >= g_count * 3) return;
  int g = t / 3, c = t % 3;
  int cnt = gstart[g + 1] - gstart[g];
  float inv = 1.0f / (float)max(cnt, 1);
  float acc = bc[c];
#pragma unroll 8
  for (int k = 0; k < FDIM; ++k) acc += pooled[g * FDIM + k] * inv * Wc[k * 3 + c];
  out[g * 3 + c] = acc;
}

// ---------------- host ----------------

extern "C" void kernel_launch(void* const* d_in, const int* in_sizes, int n_in,
                              void* d_out, int out_size, void* d_ws, size_t ws_size,
                              hipStream_t stream) {
  const float* x = (const float*)d_in[0];
  const int* edge = (const int*)d_in[1];
  const int* batch = (const int*)d_in[2];
  const float* W1 = (const float*)d_in[3];
  const float* b1 = (const float*)d_in[4];
  const float* W2 = (const float*)d_in[5];
  const float* b2 = (const float*)d_in[6];
  const float* W3 = (const float*)d_in[7];
  const float* b3 = (const float*)d_in[8];
  const float* Wc = (const float*)d_in[9];
  const float* bc = (const float*)d_in[10];
  float* out = (float*)d_out;

  const int N = in_sizes[0] / FDIM;
  const int E = in_sizes[1] / 2;
  const int G = out_size / 3;
  const int* src = edge;
  const int* dst = edge + E;

  const int NCH = (E + CHUNK - 1) / CHUNK;
  const int NB = (N + (1 << BSHIFT) - 1) >> BSHIFT;

  char* ws = (char*)d_ws;
  size_t off = 0;
  auto carve = [&](size_t bytes) -> void* {
    void* p = ws + off;
    off = (off + bytes + 255) & ~(size_t)255;
    return p;
  };
  ushort_t* h0 = (ushort_t*)carve((size_t)N * FDIM * 2);  // bf16 activations
  ushort_t* h1 = (ushort_t*)carve((size_t)N * FDIM * 2);
  int* colIdx = (int*)carve((size_t)E * 4);
  unsigned* binned = (unsigned*)carve((size_t)E * 4);
  int* chunkHist = (int*)carve((size_t)NCH * NB * 4);
  int* chunkOff = (int*)carve((size_t)NCH * NB * 4);
  int* bucketBase = (int*)carve((size_t)(NB + 1) * 4);
  int* rowStart = (int*)carve((size_t)N * 4);
  int* deg = (int*)carve((size_t)N * 4);
  float* dis = (float*)carve((size_t)N * 4);
  int* gstart = (int*)carve((size_t)(G + 1) * 4);
  float* pooled = (float*)carve((size_t)G * FDIM * 4);
  ushort_t* wsw = (ushort_t*)carve((size_t)3 * 16384 * 2);  // swizzled bf16 W
  (void)n_in;
  (void)ws_size;

  hipMemsetAsync(pooled, 0, (size_t)G * FDIM * 4, stream);

  k_hist<<<NCH, 256, 0, stream>>>(dst, E, NB, chunkHist);
  k_scan<<<1, 512, 0, stream>>>(chunkHist, NCH, NB, E, chunkOff, bucketBase);
  k_bin<<<NCH, 256, 0, stream>>>(src, dst, E, NB, chunkHist, chunkOff, bucketBase,
                                 binned);
  k_fill2<<<NB, 256, 0, stream>>>(binned, bucketBase, N, rowStart, deg, dis, colIdx);
  k_prepw<<<3, 256, 0, stream>>>(W1, W2, W3, wsw);

  int mmb = (N + 127) / 128;
  k_mm<0><<<mmb, 256, 0, stream>>>(x, wsw, h0, N);
  k_agg<<<(N + 3) / 4, 256, 0, stream>>>(h0, h1, rowStart, deg, colIdx, dis, b1, N);
  k_mm<1><<<mmb, 256, 0, stream>>>(h1, wsw + 16384, h0, N);
  k_agg<<<(N + 3) / 4, 256, 0, stream>>>(h0, h1, rowStart, deg, colIdx, dis, b2, N);
  k_mm<1><<<mmb, 256, 0, stream>>>(h1, wsw + 32768, h0, N);
  k_agg<<<(N + 3) / 4, 256, 0, stream>>>(h0, h1, rowStart, deg, colIdx, dis, b3, N);

  k_gstart<<<1, 128, 0, stream>>>(batch, N, G, gstart);
  k_pool<<<G * 16, 128, 0, stream>>>(h1, gstart, pooled, G);
  k_final<<<1, 192, 0, stream>>>(pooled, gstart, Wc, bc, out, G);
}

// Round 6
// 493.605 us; speedup vs baseline: 3.1478x; 1.2011x over previous
//
#include <hip/hip_runtime.h>
#include <cstdint>
#include <cstddef>

#define FDIM 128
#define CHUNK 4096   // edges per binning chunk
#define BSHIFT 8     // 256 nodes per bucket
#define BMASK 255
#define MAXB 512     // max buckets supported (N <= 131072)

typedef unsigned short ushort_t;
typedef __attribute__((ext_vector_type(8))) short short8;   // 8 bf16 (4 VGPRs)
typedef __attribute__((ext_vector_type(4))) float floatx4;  // MFMA C/D

// bf16 helpers (bit-level, RTN-even).
__device__ inline ushort_t f2bf(float f) {
  unsigned u = __float_as_uint(f);
  u += 0x7fffu + ((u >> 16) & 1u);
  return (ushort_t)(u >> 16);
}
__device__ inline float bf2f(ushort_t h) {
  return __uint_as_float((unsigned)h << 16);
}

// ---------------- CSR build (bucketed) ----------------

__global__ __launch_bounds__(256) void k_hist(const int* __restrict__ dst, int e,
                                              int nb, int* __restrict__ chunkHist) {
  __shared__ int h[MAXB];
  int c = blockIdx.x;
  int base = c * CHUNK;
  int end = min(base + CHUNK, e);
  for (int i = threadIdx.x; i < nb; i += 256) h[i] = 0;
  __syncthreads();
  for (int i = base + threadIdx.x; i < end; i += 256)
    atomicAdd(&h[dst[i] >> BSHIFT], 1);
  __syncthreads();
  for (int b = threadIdx.x; b < nb; b += 256)
    chunkHist[(size_t)c * nb + b] = h[b];
}

// Per-bucket scan over the chunk axis (one block per bucket). Replaces the
// single-block serial k_scan that was 101 us (391-deep dependent global
// chain on ONE CU). 512-wide Hillis-Steele, tiled if nchunks > 512.
__global__ __launch_bounds__(512) void k_scan1(const int* __restrict__ chunkHist,
                                               int nchunks, int nb,
                                               int* __restrict__ chunkOff,
                                               int* __restrict__ bucketTotal) {
  __shared__ int sb[512];
  int b = blockIdx.x;
  int t = threadIdx.x;
  int base = 0;
  for (int c0 = 0; c0 < nchunks; c0 += 512) {
    int c = c0 + t;
    int v = (c < nchunks) ? chunkHist[(size_t)c * nb + b] : 0;
    int x = v;
    sb[t] = x;
    __syncthreads();
    for (int off = 1; off < 512; off <<= 1) {
      int y = (t >= off) ? sb[t - off] : 0;
      __syncthreads();
      x += y;
      sb[t] = x;
      __syncthreads();
    }
    if (c < nchunks) chunkOff[(size_t)c * nb + b] = base + x - v;
    int tileTot = sb[511];
    __syncthreads();
    base += tileTot;
  }
  if (t == 0) bucketTotal[b] = base;
}

// Scan bucket totals -> bucketBase (1 small block, ~nb<=512 elements).
__global__ __launch_bounds__(512) void k_scan2(const int* __restrict__ bucketTotal,
                                               int nb, int e,
                                               int* __restrict__ bucketBase) {
  __shared__ int sb[512];
  int t = threadIdx.x;
  int v = (t < nb) ? bucketTotal[t] : 0;
  int x = v;
  sb[t] = x;
  __syncthreads();
  for (int off = 1; off < 512; off <<= 1) {
    int y = (t >= off) ? sb[t - off] : 0;
    __syncthreads();
    x += y;
    sb[t] = x;
    __syncthreads();
  }
  if (t < nb) bucketBase[t] = x - v;
  if (t == 0) bucketBase[nb] = e;
}

__global__ __launch_bounds__(256) void k_bin(const int* __restrict__ src,
                                             const int* __restrict__ dst, int e, int nb,
                                             const int* __restrict__ chunkHist,
                                             const int* __restrict__ chunkOff,
                                             const int* __restrict__ bucketBase,
                                             unsigned* __restrict__ binned) {
  __shared__ unsigned sortedL[CHUNK];
  __shared__ int gtarget[CHUNK];
  __shared__ int lbase[MAXB], lcur[MAXB], gbase[MAXB];
  __shared__ int stmp[256];
  int c = blockIdx.x;
  int base = c * CHUNK;
  int end = min(base + CHUNK, e);
  for (int i = threadIdx.x; i < nb; i += 256) {
    lbase[i] = chunkHist[(size_t)c * nb + i];  // temp: counts
    gbase[i] = bucketBase[i] + chunkOff[(size_t)c * nb + i];
  }
  __syncthreads();
  // tiled parallel exclusive scan of lbase[0..nb) (was serial on thread 0)
  int carry = 0;
  for (int i0 = 0; i0 < nb; i0 += 256) {
    int i = i0 + threadIdx.x;
    int v = (i < nb) ? lbase[i] : 0;
    int x = v;
    stmp[threadIdx.x] = x;
    __syncthreads();
    for (int off = 1; off < 256; off <<= 1) {
      int y = (threadIdx.x >= off) ? stmp[threadIdx.x - off] : 0;
      __syncthreads();
      x += y;
      stmp[threadIdx.x] = x;
      __syncthreads();
    }
    if (i < nb) lbase[i] = carry + x - v;
    int tileTot = stmp[255];
    __syncthreads();
    carry += tileTot;
  }
  for (int i = threadIdx.x; i < nb; i += 256) lcur[i] = lbase[i];
  __syncthreads();
  for (int i = base + threadIdx.x; i < end; i += 256) {
    int d = dst[i];
    int sv = src[i];
    int b = d >> BSHIFT;
    int slot = atomicAdd(&lcur[b], 1);
    sortedL[slot] = ((unsigned)sv << BSHIFT) | (unsigned)(d & BMASK);
    gtarget[slot] = gbase[b] + (slot - lbase[b]);
  }
  __syncthreads();
  for (int i = threadIdx.x; i < end - base; i += 256)
    binned[gtarget[i]] = sortedL[i];
}

__global__ __launch_bounds__(256) void k_fill2(const unsigned* __restrict__ binned,
                                               const int* __restrict__ bucketBase, int n,
                                               int* __restrict__ rowStart,
                                               int* __restrict__ deg,
                                               float* __restrict__ dis,
                                               int* __restrict__ colIdx) {
  __shared__ int h[256], sb[256], cur[256];
  int b = blockIdx.x;
  int s0 = bucketBase[b], s1 = bucketBase[b + 1];
  int nodeBase = b << BSHIFT;
  int t = threadIdx.x;
  h[t] = 0;
  __syncthreads();
  for (int i = s0 + t; i < s1; i += 256) atomicAdd(&h[binned[i] & BMASK], 1);
  __syncthreads();
  int v = h[t];
  int x = v;
  sb[t] = x;
  __syncthreads();
  for (int off = 1; off < 256; off <<= 1) {
    int y = (t >= off) ? sb[t - off] : 0;
    __syncthreads();
    x += y;
    sb[t] = x;
    __syncthreads();
  }
  int start = s0 + x - v;
  cur[t] = start;
  int node = nodeBase + t;
  if (node < n) {
    rowStart[node] = start;
    deg[node] = v;
    dis[node] = rsqrtf((float)(v + 1));  // +1 self-loop
  }
  __syncthreads();
  for (int i = s0 + t; i < s1; i += 256) {
    unsigned en = binned[i];
    int slot = atomicAdd(&cur[en & BMASK], 1);
    colIdx[slot] = (int)(en >> BSHIFT);
  }
}

// ---------------- W prep: fp32 -> bf16, swizzled into B-fragment order ----
// For mfma_f32_16x16x32_bf16, B fragment: lane holds B[k = (lane>>4)*8 + j]
// [n = lane&15], j=0..7 contiguous. One 16B LDS read per frag, conflict-free.
__global__ __launch_bounds__(256) void k_prepw(const float* __restrict__ W1,
                                               const float* __restrict__ W2,
                                               const float* __restrict__ W3,
                                               ushort_t* __restrict__ out) {
  int b = blockIdx.x;
  const float* W = (b == 0) ? W1 : (b == 1) ? W2 : W3;
  ushort_t* o = out + (size_t)b * 16384;
  for (int idx = threadIdx.x; idx < 16384; idx += 256) {
    int j = idx & 7;
    int lane = (idx >> 3) & 63;
    int ct = (idx >> 9) & 7;
    int kc = idx >> 12;
    int k = kc * 32 + (lane >> 4) * 8 + j;
    int col = ct * 16 + (lane & 15);
    o[idx] = f2bf(W[k * FDIM + col]);
  }
}

// ---------------- MFMA matmul: O[n,128] = A[n,128] @ W[128,128] ----------------
// bf16 inputs, fp32 accumulate. Block = 4 waves x 32 rows = 128 rows.
template <int INBF>
__global__ __launch_bounds__(256) void k_mm(const void* __restrict__ Ain,
                                            const ushort_t* __restrict__ Wsw,
                                            ushort_t* __restrict__ O, int n) {
  __shared__ ushort_t Bs[16384];  // 32 KB
  int tid = threadIdx.x;
  for (int q = tid; q < 2048; q += 256)
    ((uint4*)Bs)[q] = ((const uint4*)Wsw)[q];
  __syncthreads();

  int w = tid >> 6;
  int lane = tid & 63;
  int quad = lane >> 4;
  int l15 = lane & 15;
  int rb = blockIdx.x * 128 + w * 32;
  const float* Af = (const float*)Ain;
  const ushort_t* Ab = (const ushort_t*)Ain;

  int row0 = rb + l15;        // rt=0 A-row
  int row1 = rb + 16 + l15;   // rt=1 A-row
  bool v0 = row0 < n, v1 = row1 < n;

  floatx4 acc[2][8];
#pragma unroll
  for (int rt = 0; rt < 2; ++rt)
#pragma unroll
    for (int ct = 0; ct < 8; ++ct) acc[rt][ct] = floatx4{0.f, 0.f, 0.f, 0.f};

#pragma unroll
  for (int kc = 0; kc < 4; ++kc) {
    int k0 = kc * 32 + quad * 8;
    short8 a0 = short8{0, 0, 0, 0, 0, 0, 0, 0};
    short8 a1 = short8{0, 0, 0, 0, 0, 0, 0, 0};
    if (INBF) {
      if (v0) a0 = *(const short8*)&Ab[(size_t)row0 * FDIM + k0];
      if (v1) a1 = *(const short8*)&Ab[(size_t)row1 * FDIM + k0];
    } else {
      if (v0) {
        float4 f0 = *(const float4*)&Af[(size_t)row0 * FDIM + k0];
        float4 f1 = *(const float4*)&Af[(size_t)row0 * FDIM + k0 + 4];
        a0 = short8{(short)f2bf(f0.x), (short)f2bf(f0.y), (short)f2bf(f0.z),
                    (short)f2bf(f0.w), (short)f2bf(f1.x), (short)f2bf(f1.y),
                    (short)f2bf(f1.z), (short)f2bf(f1.w)};
      }
      if (v1) {
        float4 f0 = *(const float4*)&Af[(size_t)row1 * FDIM + k0];
        float4 f1 = *(const float4*)&Af[(size_t)row1 * FDIM + k0 + 4];
        a1 = short8{(short)f2bf(f0.x), (short)f2bf(f0.y), (short)f2bf(f0.z),
                    (short)f2bf(f0.w), (short)f2bf(f1.x), (short)f2bf(f1.y),
                    (short)f2bf(f1.z), (short)f2bf(f1.w)};
      }
    }
#pragma unroll
    for (int ct = 0; ct < 8; ++ct) {
      short8 bf = *(const short8*)&Bs[((kc * 8 + ct) * 64 + lane) * 8];
      acc[0][ct] = __builtin_amdgcn_mfma_f32_16x16x32_bf16(a0, bf, acc[0][ct], 0, 0, 0);
      acc[1][ct] = __builtin_amdgcn_mfma_f32_16x16x32_bf16(a1, bf, acc[1][ct], 0, 0, 0);
    }
  }

  // C/D layout: col = lane&15, row = quad*4 + i  (within 16x16 tile)
#pragma unroll
  for (int rt = 0; rt < 2; ++rt) {
#pragma unroll
    for (int i = 0; i < 4; ++i) {
      int row = rb + rt * 16 + quad * 4 + i;
      if (row < n) {
#pragma unroll
        for (int ct = 0; ct < 8; ++ct)
          O[(size_t)row * FDIM + ct * 16 + l15] = f2bf(acc[rt][ct][i]);
      }
    }
  }
}

// ---------------- aggregation (pull) + bias + ReLU, bf16 H ----------------
__global__ __launch_bounds__(256) void k_agg(const ushort_t* __restrict__ Hin,
                                             ushort_t* __restrict__ Hout,
                                             const int* __restrict__ rowStart,
                                             const int* __restrict__ degE,
                                             const int* __restrict__ colIdx,
                                             const float* __restrict__ dis,
                                             const float* __restrict__ bias, int n) {
  int node = blockIdx.x * 4 + (threadIdx.x >> 6);
  int lane = threadIdx.x & 63;
  if (node >= n) return;
  const unsigned* hin = (const unsigned*)Hin;  // row stride 64 uints
  float di = dis[node];
  unsigned us = hin[(size_t)node * 64 + lane];
  float ws = di * di;
  float ax = ws * __uint_as_float(us << 16);
  float ay = ws * __uint_as_float(us & 0xffff0000u);
  int s0 = rowStart[node], cnt = degE[node];
#pragma unroll 4
  for (int j = 0; j < cnt; ++j) {
    int s = colIdx[s0 + j];
    float w = di * dis[s];
    unsigned u = hin[(size_t)s * 64 + lane];
    ax += w * __uint_as_float(u << 16);
    ay += w * __uint_as_float(u & 0xffff0000u);
  }
  float2 b = ((const float2*)bias)[lane];
  ax = fmaxf(ax + b.x, 0.f);
  ay = fmaxf(ay + b.y, 0.f);
  unsigned out = (unsigned)f2bf(ax) | ((unsigned)f2bf(ay) << 16);
  ((unsigned*)Hout)[(size_t)node * 64 + lane] = out;
}

// ---------------- pooling ----------------

__global__ __launch_bounds__(128) void k_gstart(const int* __restrict__ batch, int n,
                                                int g_count, int* __restrict__ gstart) {
  int g = threadIdx.x;
  if (g > g_count) return;
  int lo = 0, hi = n;
  while (lo < hi) {
    int mid = (lo + hi) >> 1;
    if (batch[mid] < g) lo = mid + 1;
    else hi = mid;
  }
  gstart[g] = lo;
}

__global__ __launch_bounds__(128) void k_pool(const ushort_t* __restrict__ H,
                                              const int* __restrict__ gstart,
                                              float* __restrict__ pooled, int g_count) {
  int g = blockIdx.x >> 4;
  int c = blockIdx.x & 15;
  int s = gstart[g], e = gstart[g + 1];
  int len = e - s;
  int chunk = (len + 15) >> 4;
  int ns = s + c * chunk;
  int ne = min(ns + chunk, e);
  float acc = 0.f;
  for (int i = ns; i < ne; ++i) acc += bf2f(H[(size_t)i * FDIM + threadIdx.x]);
  atomicAdd(&pooled[g * FDIM + threadIdx.x], acc);
}

__global__ __launch_bounds__(192) void k_final(const float* __restrict__ pooled,
                                               const int* __restrict__ gstart,
                                               const float* __restrict__ Wc,
                                               const float* __restrict__ bc,
                                               float* __restrict__ out, int g_count) {
  int t = threadIdx.x;
  if (t >= g_count * 3) return;
  int g = t / 3, c = t % 3;
  int cnt = gstart[g + 1] - gstart[g];
  float inv = 1.0f / (float)max(cnt, 1);
  float acc = bc[c];
#pragma unroll 8
  for (int k = 0; k < FDIM; ++k) acc += pooled[g * FDIM + k] * inv * Wc[k * 3 + c];
  out[g * 3 + c] = acc;
}

// ---------------- host ----------------

extern "C" void kernel_launch(void* const* d_in, const int* in_sizes, int n_in,
                              void* d_out, int out_size, void* d_ws, size_t ws_size,
                              hipStream_t stream) {
  const float* x = (const float*)d_in[0];
  const int* edge = (const int*)d_in[1];
  const int* batch = (const int*)d_in[2];
  const float* W1 = (const float*)d_in[3];
  const float* b1 = (const float*)d_in[4];
  const float* W2 = (const float*)d_in[5];
  const float* b2 = (const float*)d_in[6];
  const float* W3 = (const float*)d_in[7];
  const float* b3 = (const float*)d_in[8];
  const float* Wc = (const float*)d_in[9];
  const float* bc = (const float*)d_in[10];
  float* out = (float*)d_out;

  const int N = in_sizes[0] / FDIM;
  const int E = in_sizes[1] / 2;
  const int G = out_size / 3;
  const int* src = edge;
  const int* dst = edge + E;

  const int NCH = (E + CHUNK - 1) / CHUNK;
  const int NB = (N + (1 << BSHIFT) - 1) >> BSHIFT;

  char* ws = (char*)d_ws;
  size_t off = 0;
  auto carve = [&](size_t bytes) -> void* {
    void* p = ws + off;
    off = (off + bytes + 255) & ~(size_t)255;
    return p;
  };
  ushort_t* h0 = (ushort_t*)carve((size_t)N * FDIM * 2);  // bf16 activations
  ushort_t* h1 = (ushort_t*)carve((size_t)N * FDIM * 2);
  int* colIdx = (int*)carve((size_t)E * 4);
  unsigned* binned = (unsigned*)carve((size_t)E * 4);
  int* chunkHist = (int*)carve((size_t)NCH * NB * 4);
  int* chunkOff = (int*)carve((size_t)NCH * NB * 4);
  int* bucketTotal = (int*)carve((size_t)NB * 4);
  int* bucketBase = (int*)carve((size_t)(NB + 1) * 4);
  int* rowStart = (int*)carve((size_t)N * 4);
  int* deg = (int*)carve((size_t)N * 4);
  float* dis = (float*)carve((size_t)N * 4);
  int* gstart = (int*)carve((size_t)(G + 1) * 4);
  float* pooled = (float*)carve((size_t)G * FDIM * 4);
  ushort_t* wsw = (ushort_t*)carve((size_t)3 * 16384 * 2);  // swizzled bf16 W
  (void)n_in;
  (void)ws_size;

  hipMemsetAsync(pooled, 0, (size_t)G * FDIM * 4, stream);

  k_hist<<<NCH, 256, 0, stream>>>(dst, E, NB, chunkHist);
  k_scan1<<<NB, 512, 0, stream>>>(chunkHist, NCH, NB, chunkOff, bucketTotal);
  k_scan2<<<1, 512, 0, stream>>>(bucketTotal, NB, E, bucketBase);
  k_bin<<<NCH, 256, 0, stream>>>(src, dst, E, NB, chunkHist, chunkOff, bucketBase,
                                 binned);
  k_fill2<<<NB, 256, 0, stream>>>(binned, bucketBase, N, rowStart, deg, dis, colIdx);
  k_prepw<<<3, 256, 0, stream>>>(W1, W2, W3, wsw);

  int mmb = (N + 127) / 128;
  k_mm<0><<<mmb, 256, 0, stream>>>(x, wsw, h0, N);
  k_agg<<<(N + 3) / 4, 256, 0, stream>>>(h0, h1, rowStart, deg, colIdx, dis, b1, N);
  k_mm<1><<<mmb, 256, 0, stream>>>(h1, wsw + 16384, h0, N);
  k_agg<<<(N + 3) / 4, 256, 0, stream>>>(h0, h1, rowStart, deg, colIdx, dis, b2, N);
  k_mm<1><<<mmb, 256, 0, stream>>>(h1, wsw + 32768, h0, N);
  k_agg<<<(N + 3) / 4, 256, 0, stream>>>(h0, h1, rowStart, deg, colIdx, dis, b3, N);

  k_gstart<<<1, 128, 0, stream>>>(batch, N, G, gstart);
  k_pool<<<G * 16, 128, 0, stream>>>(h1, gstart, pooled, G);
  k_final<<<1, 192, 0, stream>>>(pooled, gstart, Wc, bc, out, G);
}